// Round 1
// baseline (944.339 us; speedup 1.0000x reference)
//
#include <hip/hip_runtime.h>
#include <cstdint>
#include <cstddef>

// ---------------------------------------------------------------------------
// Transformer block, MI355X bf16-MFMA implementation (round 1: correctness +
// m97-style GEMM structure). All GEMMs: C = A @ Bt^T with A,Bt row-major
// [rows][K] bf16, 128x128 block tile, BK=32, global_load_lds width=16,
// XOR-swizzled *global* chunk so LDS stays lane-linear but ds_read_b128
// fragment reads are ~2-way-conflict-free.
// ---------------------------------------------------------------------------

typedef unsigned short u16;
typedef __bf16 bf16x8 __attribute__((ext_vector_type(8)));
typedef float  f32x4  __attribute__((ext_vector_type(4)));

#define B_      2
#define T_      2048
#define C_      2048
#define NH_     16
#define NG_     4
#define HD_     128
#define QKVO_   3072      // (16 + 2*4) * 128
#define FFN_    8192
#define ROWS_   4096      // B*T

__device__ __forceinline__ u16 f2b(float f) {
  union { float f; uint32_t u; } c; c.f = f;
  uint32_t u = c.u;
  return (u16)((u + 0x7fffu + ((u >> 16) & 1u)) >> 16);  // RNE
}
__device__ __forceinline__ float b2f(u16 h) {
  union { uint32_t u; float f; } c; c.u = ((uint32_t)h) << 16;
  return c.f;
}
__device__ __forceinline__ void load_lds16(const void* g, void* l) {
  __builtin_amdgcn_global_load_lds(
      (const __attribute__((address_space(1))) uint32_t*)g,
      (__attribute__((address_space(3))) uint32_t*)l, 16, 0, 0);
}

// ---------------------------------------------------------------------------
// Kernel 1: dual LayerNorm over x rows (one mean/var, two weight sets) -> bf16
// ---------------------------------------------------------------------------
__global__ __launch_bounds__(256) void ln2x_kernel(
    const float* __restrict__ x,
    const float* __restrict__ w1, const float* __restrict__ b1,
    const float* __restrict__ w2, const float* __restrict__ b2,
    u16* __restrict__ o1, u16* __restrict__ o2)
{
  const int row = blockIdx.x;
  const float4* xr = (const float4*)(x + (size_t)row * C_);
  const int t = threadIdx.x;
  float4 v0 = xr[t];
  float4 v1 = xr[t + 256];
  float s  = v0.x + v0.y + v0.z + v0.w + v1.x + v1.y + v1.z + v1.w;
  float ss = v0.x*v0.x + v0.y*v0.y + v0.z*v0.z + v0.w*v0.w
           + v1.x*v1.x + v1.y*v1.y + v1.z*v1.z + v1.w*v1.w;
#pragma unroll
  for (int o = 32; o; o >>= 1) { s += __shfl_down(s, o); ss += __shfl_down(ss, o); }
  __shared__ float red[8];
  const int w = t >> 6;
  if ((t & 63) == 0) { red[w] = s; red[4 + w] = ss; }
  __syncthreads();
  s  = red[0] + red[1] + red[2] + red[3];
  ss = red[4] + red[5] + red[6] + red[7];
  const float mu   = s * (1.0f / C_);
  const float rstd = rsqrtf(ss * (1.0f / C_) - mu * mu + 1e-5f);

  const float4* W1 = (const float4*)w1; const float4* B1 = (const float4*)b1;
  const float4* W2 = (const float4*)w2; const float4* B2 = (const float4*)b2;
#pragma unroll
  for (int c = 0; c < 2; ++c) {
    const int idx = t + c * 256;
    float4 v = (c == 0) ? v0 : v1;
    float n0 = (v.x - mu) * rstd, n1 = (v.y - mu) * rstd;
    float n2 = (v.z - mu) * rstd, n3 = (v.w - mu) * rstd;
    float4 a1 = W1[idx], c1 = B1[idx], a2 = W2[idx], c2 = B2[idx];
    uint64_t p1 = (uint64_t)f2b(n0*a1.x + c1.x)
                | ((uint64_t)f2b(n1*a1.y + c1.y) << 16)
                | ((uint64_t)f2b(n2*a1.z + c1.z) << 32)
                | ((uint64_t)f2b(n3*a1.w + c1.w) << 48);
    uint64_t p2 = (uint64_t)f2b(n0*a2.x + c2.x)
                | ((uint64_t)f2b(n1*a2.y + c2.y) << 16)
                | ((uint64_t)f2b(n2*a2.z + c2.z) << 32)
                | ((uint64_t)f2b(n3*a2.w + c2.w) << 48);
    ((uint64_t*)o1)[(size_t)row * (C_/4) + idx] = p1;
    ((uint64_t*)o2)[(size_t)row * (C_/4) + idx] = p2;
  }
}

// ---------------------------------------------------------------------------
// Kernel 2: transpose + fp32->bf16 cast:  in[R][Ccols] -> out[Ccols][R]
// ---------------------------------------------------------------------------
__global__ void tcast_kernel(const float* __restrict__ in, u16* __restrict__ out,
                             int R, int Ccols)
{
  __shared__ float tile[32][33];
  const int c0 = blockIdx.x * 32, r0 = blockIdx.y * 32;
  const int tx = threadIdx.x, ty = threadIdx.y;
#pragma unroll
  for (int i = 0; i < 4; ++i)
    tile[ty + i*8][tx] = in[(size_t)(r0 + ty + i*8) * Ccols + c0 + tx];
  __syncthreads();
#pragma unroll
  for (int i = 0; i < 4; ++i)
    out[(size_t)(c0 + ty + i*8) * R + r0 + tx] = f2b(tile[tx][ty + i*8]);
}

// ---------------------------------------------------------------------------
// Kernel 3: GEMM  C[M][N] = A[M][K] @ Bt[N][K]^T  (+bias, epilogue variants)
// EPI 0: +bias -> bf16 out;  1: +bias, exact GELU -> bf16;  2: +bias+resid -> f32
// ---------------------------------------------------------------------------
template <int EPI>
__global__ __launch_bounds__(256, 2) void gemm_bt(
    const u16* __restrict__ A, const u16* __restrict__ Bt,
    const float* __restrict__ bias, const float* __restrict__ resid,
    u16* __restrict__ outB, float* __restrict__ outF,
    int M, int N, int K)
{
  __shared__ u16 As[128 * 32];
  __shared__ u16 Bs[128 * 32];
  const int tid = threadIdx.x;
  const int w = tid >> 6, lane = tid & 63, quad = lane >> 4, l16 = lane & 15;
  const int wm = w >> 1, wn = w & 1;
  const int m0 = blockIdx.y * 128, n0 = blockIdx.x * 128;

  const f32x4 vzero = {0.f, 0.f, 0.f, 0.f};
  f32x4 acc[4][4];
#pragma unroll
  for (int i = 0; i < 4; ++i)
#pragma unroll
    for (int j = 0; j < 4; ++j) acc[i][j] = vzero;

  const u16* Ap = A  + (size_t)m0 * K;
  const u16* Bp = Bt + (size_t)n0 * K;
  const int rowS = tid >> 2;     // staging row (i=0), +64 for i=1
  const int slotS = tid & 3;

  for (int k0 = 0; k0 < K; k0 += 32) {
    __syncthreads();
#pragma unroll
    for (int i = 0; i < 2; ++i) {
      int row = rowS + i * 64;
      int chunk = slotS ^ ((row >> 1) & 3);        // global-side swizzle
      load_lds16(Ap + (size_t)row * K + k0 + chunk * 8, (char*)As + i * 4096 + w * 1024);
      load_lds16(Bp + (size_t)row * K + k0 + chunk * 8, (char*)Bs + i * 4096 + w * 1024);
    }
    __syncthreads();

    bf16x8 af[4], bf[4];
#pragma unroll
    for (int mt = 0; mt < 4; ++mt) {
      int row = wm * 64 + mt * 16 + l16;
      int slot = quad ^ ((row >> 1) & 3);
      af[mt] = *(const bf16x8*)(As + row * 32 + slot * 8);
    }
#pragma unroll
    for (int nt = 0; nt < 4; ++nt) {
      int row = wn * 64 + nt * 16 + l16;
      int slot = quad ^ ((row >> 1) & 3);
      bf[nt] = *(const bf16x8*)(Bs + row * 32 + slot * 8);
    }
#pragma unroll
    for (int mt = 0; mt < 4; ++mt)
#pragma unroll
      for (int nt = 0; nt < 4; ++nt)
        acc[mt][nt] = __builtin_amdgcn_mfma_f32_16x16x32_bf16(af[mt], bf[nt], acc[mt][nt], 0, 0, 0);
  }

#pragma unroll
  for (int mt = 0; mt < 4; ++mt)
#pragma unroll
    for (int nt = 0; nt < 4; ++nt)
#pragma unroll
      for (int r = 0; r < 4; ++r) {
        int row = m0 + wm * 64 + mt * 16 + quad * 4 + r;   // C/D: row=quad*4+reg
        int col = n0 + wn * 64 + nt * 16 + l16;            //      col=lane&15
        float v = acc[mt][nt][r] + bias[col];
        if constexpr (EPI == 1)
          v = 0.5f * v * (1.0f + erff(v * 0.70710678118654752f));
        if constexpr (EPI == 2) {
          v += resid[(size_t)row * N + col];
          outF[(size_t)row * N + col] = v;
        } else {
          outB[(size_t)row * N + col] = f2b(v);
        }
      }
}

// ---------------------------------------------------------------------------
// Kernel 4: RoPE + scatter qkv(bf16) -> qbuf [B,NH,T,D], kbuf [B,NG,T,D]
// qkv token layout: [g][s][d], s=0..3 q-heads, s=4 k, s=5 v
// ---------------------------------------------------------------------------
__global__ __launch_bounds__(256) void rope_kernel(
    const u16* __restrict__ qkv, const float* __restrict__ cosb,
    const float* __restrict__ sinb, u16* __restrict__ qb, u16* __restrict__ kb)
{
  const int bt = blockIdx.x;
  const int b = bt >> 11, t = bt & 2047;
  const u16* base = qkv + (size_t)bt * QKVO_;
  const int d = threadIdx.x & 127;
  const int half = threadIdx.x >> 7;
  for (int it = 0; it < 10; ++it) {
    const int slot = it * 2 + half;   // 0..15 q-heads, 16..19 k-groups
    int col;
    if (slot < 16) {
      int g = slot >> 2, s = slot & 3;
      col = g * 768 + s * 128 + d;
    } else {
      col = (slot - 16) * 768 + 512 + d;
    }
    float v = b2f(base[col]);
    if (d < 32) {
      float cs = cosb[t * 32 + d], sn = sinb[t * 32 + d];
      if (d < 16) v = v * cs - b2f(base[col + 16]) * sn;
      else        v = v * cs + b2f(base[col - 16]) * sn;
    }
    if (slot < 16)
      qb[((size_t)(b * NH_ + slot) * T_ + t) * HD_ + d] = f2b(v);
    else
      kb[((size_t)(b * NG_ + (slot - 16)) * T_ + t) * HD_ + d] = f2b(v);
  }
}

// ---------------------------------------------------------------------------
// Kernel 5: V transpose: qkv v-slice -> vtb [B,NG,D,T]  (bf16 tile transpose)
// ---------------------------------------------------------------------------
__global__ void vtrans_kernel(const u16* __restrict__ qkv, u16* __restrict__ vtb)
{
  __shared__ u16 tile[32][33];
  const int bg = blockIdx.z, b = bg >> 2, g = bg & 3;
  const int t0 = blockIdx.x * 32, d0 = blockIdx.y * 32;
  const int tx = threadIdx.x, ty = threadIdx.y;
#pragma unroll
  for (int i = 0; i < 4; ++i)
    tile[ty + i*8][tx] =
        qkv[(size_t)(b * T_ + t0 + ty + i*8) * QKVO_ + g * 768 + 640 + d0 + tx];
  __syncthreads();
#pragma unroll
  for (int i = 0; i < 4; ++i)
    vtb[((size_t)(b * NG_ + g) * HD_ + d0 + ty + i*8) * T_ + t0 + tx] =
        tile[tx][ty + i*8];
}

// ---------------------------------------------------------------------------
// Kernel 6: flash attention, causal, GQA. BQ=64 (16 rows/wave), BKV=64.
// ---------------------------------------------------------------------------
__global__ __launch_bounds__(256, 2) void attn_kernel(
    const u16* __restrict__ qb, const u16* __restrict__ kb,
    const u16* __restrict__ vt, u16* __restrict__ y)
{
  __shared__ u16 Qs[64 * 128];
  __shared__ u16 Ks[64 * 128];
  __shared__ u16 Vs[128 * 64];      // V^T tile: [d][kv]
  __shared__ u16 Ps[4 * 16 * 64];   // per-wave P

  const int tid = threadIdx.x;
  const int w = tid >> 6, lane = tid & 63, quad = lane >> 4, l16 = lane & 15;
  const int b = blockIdx.y >> 4, h = blockIdx.y & 15, g = h >> 2;
  const int q0 = blockIdx.x * 64;

  const u16* Qg = qb + (size_t)(b * NH_ + h) * T_ * HD_;
  const u16* Kg = kb + (size_t)(b * NG_ + g) * T_ * HD_;
  const u16* Vg = vt + (size_t)(b * NG_ + g) * HD_ * T_;

  {  // stage Q tile once (16 KB)
    const int row = tid >> 4, slot = tid & 15;
#pragma unroll
    for (int i = 0; i < 4; ++i) {
      int r = row + i * 16;
      int chunk = slot ^ (r & 7);
      load_lds16(Qg + (size_t)(q0 + r) * HD_ + chunk * 8, (char*)Qs + i * 4096 + w * 1024);
    }
  }

  const f32x4 vzero = {0.f, 0.f, 0.f, 0.f};
  float m_run[4] = {-1e30f, -1e30f, -1e30f, -1e30f};
  float l_run[4] = {0.f, 0.f, 0.f, 0.f};
  f32x4 O[8];
#pragma unroll
  for (int nt = 0; nt < 8; ++nt) O[nt] = vzero;

  const float scale = 0.08838834764831845f;  // 1/sqrt(128)
  const int rowK = tid >> 4, slotK = tid & 15;
  const int rowV = tid >> 3, slotV = tid & 7;

  for (int j = 0; j <= (int)blockIdx.x; ++j) {
    const int kv0 = j * 64;
    __syncthreads();
#pragma unroll
    for (int i = 0; i < 4; ++i) {
      int r = rowK + i * 16;
      int chunk = slotK ^ (r & 7);
      load_lds16(Kg + (size_t)(kv0 + r) * HD_ + chunk * 8, (char*)Ks + i * 4096 + w * 1024);
    }
#pragma unroll
    for (int i = 0; i < 4; ++i) {
      int r = rowV + i * 32;
      int chunk = slotV ^ (r & 7);
      load_lds16(Vg + (size_t)r * T_ + kv0 + chunk * 8, (char*)Vs + i * 4096 + w * 1024);
    }
    __syncthreads();

    // S = Q K^T  (wave's 16 q-rows x 64 kv)
    bf16x8 aq[4];
#pragma unroll
    for (int kk = 0; kk < 4; ++kk) {
      int row = w * 16 + l16;
      int slot = (kk * 4 + quad) ^ (row & 7);
      aq[kk] = *(const bf16x8*)(Qs + row * 128 + slot * 8);
    }
    f32x4 S[4];
#pragma unroll
    for (int jn = 0; jn < 4; ++jn) {
      f32x4 a = vzero;
#pragma unroll
      for (int kk = 0; kk < 4; ++kk) {
        int row = jn * 16 + l16;
        int slot = (kk * 4 + quad) ^ (row & 7);
        bf16x8 bk = *(const bf16x8*)(Ks + row * 128 + slot * 8);
        a = __builtin_amdgcn_mfma_f32_16x16x32_bf16(aq[kk], bk, a, 0, 0, 0);
      }
      S[jn] = a;
    }

    // scale + causal mask
#pragma unroll
    for (int jn = 0; jn < 4; ++jn) {
      int col = kv0 + jn * 16 + l16;
#pragma unroll
      for (int r = 0; r < 4; ++r) {
        int qrow = q0 + w * 16 + quad * 4 + r;
        float v = S[jn][r] * scale;
        S[jn][r] = (col <= qrow) ? v : -1e30f;
      }
    }

    // row-max over 16 lanes of each quad
    float mx[4];
#pragma unroll
    for (int r = 0; r < 4; ++r)
      mx[r] = fmaxf(fmaxf(S[0][r], S[1][r]), fmaxf(S[2][r], S[3][r]));
#pragma unroll
    for (int d = 1; d < 16; d <<= 1)
#pragma unroll
      for (int r = 0; r < 4; ++r) mx[r] = fmaxf(mx[r], __shfl_xor(mx[r], d));

    float alpha[4];
#pragma unroll
    for (int r = 0; r < 4; ++r) {
      float mn = fmaxf(m_run[r], mx[r]);
      alpha[r] = __expf(m_run[r] - mn);
      m_run[r] = mn;
    }
    float rs[4] = {0.f, 0.f, 0.f, 0.f};
#pragma unroll
    for (int jn = 0; jn < 4; ++jn)
#pragma unroll
      for (int r = 0; r < 4; ++r) {
        float p = __expf(S[jn][r] - m_run[r]);
        S[jn][r] = p;
        rs[r] += p;
      }
#pragma unroll
    for (int d = 1; d < 16; d <<= 1)
#pragma unroll
      for (int r = 0; r < 4; ++r) rs[r] += __shfl_xor(rs[r], d);
#pragma unroll
    for (int r = 0; r < 4; ++r) l_run[r] = l_run[r] * alpha[r] + rs[r];
#pragma unroll
    for (int nt = 0; nt < 8; ++nt)
#pragma unroll
      for (int r = 0; r < 4; ++r) O[nt][r] *= alpha[r];

    // P (C-layout) -> LDS -> A-layout; wave-private, no barrier needed
#pragma unroll
    for (int jn = 0; jn < 4; ++jn)
#pragma unroll
      for (int r = 0; r < 4; ++r) {
        int row = quad * 4 + r;
        int col = jn * 16 + l16;
        int slot = (col >> 3) ^ (row & 7);
        Ps[w * 1024 + row * 64 + slot * 8 + (col & 7)] = f2b(S[jn][r]);
      }

    // O += P V
    bf16x8 ap[2];
#pragma unroll
    for (int kk = 0; kk < 2; ++kk) {
      int slot = (kk * 4 + quad) ^ (l16 & 7);
      ap[kk] = *(const bf16x8*)(Ps + w * 1024 + l16 * 64 + slot * 8);
    }
#pragma unroll
    for (int nt = 0; nt < 8; ++nt) {
#pragma unroll
      for (int kk = 0; kk < 2; ++kk) {
        int row = nt * 16 + l16;
        int slot = (kk * 4 + quad) ^ (row & 7);
        bf16x8 bv = *(const bf16x8*)(Vs + row * 64 + slot * 8);
        O[nt] = __builtin_amdgcn_mfma_f32_16x16x32_bf16(ap[kk], bv, O[nt], 0, 0, 0);
      }
    }
  }

  // epilogue: O/l -> y [B,T,C] bf16 (head h occupies cols h*128..)
#pragma unroll
  for (int r = 0; r < 4; ++r) {
    float inv = 1.0f / l_run[r];
    int t = q0 + w * 16 + quad * 4 + r;
    size_t base = (size_t)(b * T_ + t) * C_ + h * HD_;
#pragma unroll
    for (int nt = 0; nt < 8; ++nt)
      y[base + nt * 16 + l16] = f2b(O[nt][r] * inv);
  }
}

// ---------------------------------------------------------------------------
extern "C" void kernel_launch(void* const* d_in, const int* in_sizes, int n_in,
                              void* d_out, int out_size, void* d_ws, size_t ws_size,
                              hipStream_t stream)
{
  const float* x     = (const float*)d_in[0];
  const float* cosb  = (const float*)d_in[1];
  const float* sinb  = (const float*)d_in[2];
  const float* ln1w  = (const float*)d_in[3];
  const float* ln1b  = (const float*)d_in[4];
  const float* wqkv  = (const float*)d_in[5];
  const float* bqkv  = (const float*)d_in[6];
  const float* wproj = (const float*)d_in[7];
  const float* bproj = (const float*)d_in[8];
  const float* ln2w  = (const float*)d_in[9];
  const float* ln2b  = (const float*)d_in[10];
  const float* wfc1  = (const float*)d_in[11];
  const float* bfc1  = (const float*)d_in[12];
  const float* wfc2  = (const float*)d_in[13];
  const float* bfc2  = (const float*)d_in[14];
  float* out = (float*)d_out;

  char* ws = (char*)d_ws;
  size_t off = 0;
  auto alloc = [&](size_t bytes) -> char* {
    char* p = ws + off;
    off += (bytes + 255) & ~(size_t)255;
    return p;
  };
  u16* ln1    = (u16*)alloc((size_t)ROWS_ * C_ * 2);
  u16* ln2    = (u16*)alloc((size_t)ROWS_ * C_ * 2);
  u16* wqkvT  = (u16*)alloc((size_t)QKVO_ * C_ * 2);
  u16* wprojT = (u16*)alloc((size_t)C_ * C_ * 2);
  u16* wfc1T  = (u16*)alloc((size_t)FFN_ * C_ * 2);
  u16* wfc2T  = (u16*)alloc((size_t)C_ * FFN_ * 2);
  u16* qkv    = (u16*)alloc((size_t)ROWS_ * QKVO_ * 2);
  u16* qbuf   = (u16*)alloc((size_t)B_ * NH_ * T_ * HD_ * 2);
  u16* kbuf   = (u16*)alloc((size_t)B_ * NG_ * T_ * HD_ * 2);
  u16* vtb    = (u16*)alloc((size_t)B_ * NG_ * HD_ * T_ * 2);
  u16* ybuf   = (u16*)alloc((size_t)ROWS_ * C_ * 2);
  u16* gbuf   = (u16*)alloc((size_t)ROWS_ * FFN_ * 2);
  if (off > ws_size) return;  // workspace too small: fail loudly (wrong output)

  ln2x_kernel<<<dim3(ROWS_), dim3(256), 0, stream>>>(x, ln1w, ln1b, ln2w, ln2b, ln1, ln2);

  dim3 tb(32, 8);
  tcast_kernel<<<dim3(QKVO_/32, C_/32), tb, 0, stream>>>(wqkv, wqkvT, C_, QKVO_);
  tcast_kernel<<<dim3(C_/32,   C_/32), tb, 0, stream>>>(wproj, wprojT, C_, C_);
  tcast_kernel<<<dim3(FFN_/32, C_/32), tb, 0, stream>>>(wfc1, wfc1T, C_, FFN_);
  tcast_kernel<<<dim3(C_/32, FFN_/32), tb, 0, stream>>>(wfc2, wfc2T, FFN_, C_);

  gemm_bt<0><<<dim3(QKVO_/128, ROWS_/128), dim3(256), 0, stream>>>(
      ln1, wqkvT, bqkv, nullptr, qkv, nullptr, ROWS_, QKVO_, C_);

  rope_kernel<<<dim3(ROWS_), dim3(256), 0, stream>>>(qkv, cosb, sinb, qbuf, kbuf);
  vtrans_kernel<<<dim3(T_/32, HD_/32, B_*NG_), tb, 0, stream>>>(qkv, vtb);

  attn_kernel<<<dim3(T_/64, B_*NH_), dim3(256), 0, stream>>>(qbuf, kbuf, vtb, ybuf);

  // h + x -> d_out (fp32)
  gemm_bt<2><<<dim3(C_/128, ROWS_/128), dim3(256), 0, stream>>>(
      ybuf, wprojT, bproj, x, nullptr, out, ROWS_, C_, C_);

  // gelu(ln2 @ w_fc1 + b_fc1) -> gbuf (bf16)
  gemm_bt<1><<<dim3(FFN_/128, ROWS_/128), dim3(256), 0, stream>>>(
      ln2, wfc1T, bfc1, nullptr, gbuf, nullptr, ROWS_, FFN_, C_);

  // gbuf @ w_fc2 + b_fc2 + (h + x) -> d_out (fp32)
  gemm_bt<2><<<dim3(C_/128, ROWS_/128), dim3(256), 0, stream>>>(
      gbuf, wfc2T, bfc2, out, nullptr, out, ROWS_, C_, FFN_);
}

// Round 2
// 900.704 us; speedup vs baseline: 1.0484x; 1.0484x over previous
//
#include <hip/hip_runtime.h>
#include <cstdint>
#include <cstddef>

// ---------------------------------------------------------------------------
// Transformer block, MI355X bf16-MFMA. Round 2:
//  - FC2 split-K=2 (grid was 512 blocks = 2/CU -> occupancy-limited) + fused
//    float4 reduce.
//  - RoPE + head-scatter + V-transpose fused into the QKV GEMM epilogue
//    (rope pair (d, d+16) lives in acc[mt][0]/acc[mt][1] of the same lane).
//  - tcast: 64x64 tiles, float4 loads, ushort4 stores.
//  - attn: Q-fragment reads hoisted out of K-loop; mask only on diagonal tile.
// ---------------------------------------------------------------------------

typedef unsigned short u16;
typedef __bf16 bf16x8 __attribute__((ext_vector_type(8)));
typedef float  f32x4  __attribute__((ext_vector_type(4)));

#define B_      2
#define T_      2048
#define C_      2048
#define NH_     16
#define NG_     4
#define HD_     128
#define QKVO_   3072      // (16 + 2*4) * 128
#define FFN_    8192
#define ROWS_   4096      // B*T

__device__ __forceinline__ u16 f2b(float f) {
  union { float f; uint32_t u; } c; c.f = f;
  uint32_t u = c.u;
  return (u16)((u + 0x7fffu + ((u >> 16) & 1u)) >> 16);  // RNE
}
__device__ __forceinline__ float b2f(u16 h) {
  union { uint32_t u; float f; } c; c.u = ((uint32_t)h) << 16;
  return c.f;
}
__device__ __forceinline__ void load_lds16(const void* g, void* l) {
  __builtin_amdgcn_global_load_lds(
      (const __attribute__((address_space(1))) uint32_t*)g,
      (__attribute__((address_space(3))) uint32_t*)l, 16, 0, 0);
}

// ---------------------------------------------------------------------------
// Kernel 1: dual LayerNorm (one mean/var, two weight sets) -> bf16
// ---------------------------------------------------------------------------
__global__ __launch_bounds__(256) void ln2x_kernel(
    const float* __restrict__ x,
    const float* __restrict__ w1, const float* __restrict__ b1,
    const float* __restrict__ w2, const float* __restrict__ b2,
    u16* __restrict__ o1, u16* __restrict__ o2)
{
  const int row = blockIdx.x;
  const float4* xr = (const float4*)(x + (size_t)row * C_);
  const int t = threadIdx.x;
  float4 v0 = xr[t];
  float4 v1 = xr[t + 256];
  float s  = v0.x + v0.y + v0.z + v0.w + v1.x + v1.y + v1.z + v1.w;
  float ss = v0.x*v0.x + v0.y*v0.y + v0.z*v0.z + v0.w*v0.w
           + v1.x*v1.x + v1.y*v1.y + v1.z*v1.z + v1.w*v1.w;
#pragma unroll
  for (int o = 32; o; o >>= 1) { s += __shfl_down(s, o); ss += __shfl_down(ss, o); }
  __shared__ float red[8];
  const int w = t >> 6;
  if ((t & 63) == 0) { red[w] = s; red[4 + w] = ss; }
  __syncthreads();
  s  = red[0] + red[1] + red[2] + red[3];
  ss = red[4] + red[5] + red[6] + red[7];
  const float mu   = s * (1.0f / C_);
  const float rstd = rsqrtf(ss * (1.0f / C_) - mu * mu + 1e-5f);

  const float4* W1 = (const float4*)w1; const float4* B1 = (const float4*)b1;
  const float4* W2 = (const float4*)w2; const float4* B2 = (const float4*)b2;
#pragma unroll
  for (int c = 0; c < 2; ++c) {
    const int idx = t + c * 256;
    float4 v = (c == 0) ? v0 : v1;
    float n0 = (v.x - mu) * rstd, n1 = (v.y - mu) * rstd;
    float n2 = (v.z - mu) * rstd, n3 = (v.w - mu) * rstd;
    float4 a1 = W1[idx], c1 = B1[idx], a2 = W2[idx], c2 = B2[idx];
    uint64_t p1 = (uint64_t)f2b(n0*a1.x + c1.x)
                | ((uint64_t)f2b(n1*a1.y + c1.y) << 16)
                | ((uint64_t)f2b(n2*a1.z + c1.z) << 32)
                | ((uint64_t)f2b(n3*a1.w + c1.w) << 48);
    uint64_t p2 = (uint64_t)f2b(n0*a2.x + c2.x)
                | ((uint64_t)f2b(n1*a2.y + c2.y) << 16)
                | ((uint64_t)f2b(n2*a2.z + c2.z) << 32)
                | ((uint64_t)f2b(n3*a2.w + c2.w) << 48);
    ((uint64_t*)o1)[(size_t)row * (C_/4) + idx] = p1;
    ((uint64_t*)o2)[(size_t)row * (C_/4) + idx] = p2;
  }
}

// ---------------------------------------------------------------------------
// Kernel 2: transpose + cast fp32->bf16, 64x64 tile, float4 in / ushort4 out
// in[R][Ccols] -> out[Ccols][R]
// ---------------------------------------------------------------------------
__global__ __launch_bounds__(256) void tcast64(
    const float* __restrict__ in, u16* __restrict__ out, int R, int Ccols)
{
  __shared__ u16 tileT[64 * 72];   // [c][r], stride 72
  const int c0 = blockIdx.x * 64, r0 = blockIdx.y * 64;
  const int lin = threadIdx.x;
  {
    const int cI = (lin & 15) * 4, r = lin >> 4;    // r 0..15
#pragma unroll
    for (int i = 0; i < 4; ++i) {
      const int rr = r + i * 16;
      float4 v = *(const float4*)(in + (size_t)(r0 + rr) * Ccols + c0 + cI);
      tileT[(cI + 0) * 72 + rr] = f2b(v.x);
      tileT[(cI + 1) * 72 + rr] = f2b(v.y);
      tileT[(cI + 2) * 72 + rr] = f2b(v.z);
      tileT[(cI + 3) * 72 + rr] = f2b(v.w);
    }
  }
  __syncthreads();
  {
    const int rr = (lin & 15) * 4, cc = lin >> 4;   // cc 0..15
#pragma unroll
    for (int i = 0; i < 4; ++i) {
      const int c = cc + i * 16;
      ushort4 pk = *(const ushort4*)(tileT + c * 72 + rr);
      *(ushort4*)(out + (size_t)(c0 + c) * R + r0 + rr) = pk;
    }
  }
}

// ---------------------------------------------------------------------------
// Shared GEMM main loop: acc += A[m0..][kbeg..kend) @ Bt[n0..][kbeg..kend)^T
// A,Bt row-major bf16 with row stride K. 128x128 tile, BK=32.
// ---------------------------------------------------------------------------
__device__ __forceinline__ void gemm_loop(
    const u16* __restrict__ Ap, const u16* __restrict__ Bp,
    int K, int kbeg, int kend, f32x4 acc[4][4])
{
  __shared__ u16 As[128 * 32];
  __shared__ u16 Bs[128 * 32];
  const int tid = threadIdx.x;
  const int w = tid >> 6, lane = tid & 63, quad = lane >> 4, l16 = lane & 15;
  const int wm = w >> 1, wn = w & 1;
  const int rowS = tid >> 2, slotS = tid & 3;

  for (int k0 = kbeg; k0 < kend; k0 += 32) {
    __syncthreads();
#pragma unroll
    for (int i = 0; i < 2; ++i) {
      int row = rowS + i * 64;
      int chunk = slotS ^ ((row >> 1) & 3);        // global-side swizzle
      load_lds16(Ap + (size_t)row * K + k0 + chunk * 8, (char*)As + i * 4096 + w * 1024);
      load_lds16(Bp + (size_t)row * K + k0 + chunk * 8, (char*)Bs + i * 4096 + w * 1024);
    }
    __syncthreads();

    bf16x8 af[4], bf[4];
#pragma unroll
    for (int mt = 0; mt < 4; ++mt) {
      int row = wm * 64 + mt * 16 + l16;
      int slot = quad ^ ((row >> 1) & 3);
      af[mt] = *(const bf16x8*)(As + row * 32 + slot * 8);
    }
#pragma unroll
    for (int nt = 0; nt < 4; ++nt) {
      int row = wn * 64 + nt * 16 + l16;
      int slot = quad ^ ((row >> 1) & 3);
      bf[nt] = *(const bf16x8*)(Bs + row * 32 + slot * 8);
    }
#pragma unroll
    for (int mt = 0; mt < 4; ++mt)
#pragma unroll
      for (int nt = 0; nt < 4; ++nt)
        acc[mt][nt] = __builtin_amdgcn_mfma_f32_16x16x32_bf16(af[mt], bf[nt], acc[mt][nt], 0, 0, 0);
  }
}

#define GEMM_PROLOGUE(KSTRIDE, KBEG, KEND)                                    \
  const int tid = threadIdx.x;                                                \
  const int w = tid >> 6, lane = tid & 63, quad = lane >> 4, l16 = lane & 15; \
  const int wm = w >> 1, wn = w & 1;                                          \
  const int m0 = blockIdx.y * 128, n0 = blockIdx.x * 128;                     \
  const f32x4 vzero = {0.f, 0.f, 0.f, 0.f};                                   \
  f32x4 acc[4][4];                                                            \
  _Pragma("unroll") for (int i = 0; i < 4; ++i)                               \
    _Pragma("unroll") for (int j = 0; j < 4; ++j) acc[i][j] = vzero;          \
  gemm_loop(A + (size_t)m0 * (KSTRIDE), Bt + (size_t)n0 * (KSTRIDE),          \
            (KSTRIDE), (KBEG), (KEND), acc);

// --- QKV GEMM: epilogue fuses bias + RoPE + head scatter + V transpose -----
__global__ __launch_bounds__(256, 2) void gemm_qkv(
    const u16* __restrict__ A, const u16* __restrict__ Bt,
    const float* __restrict__ bias,
    const float* __restrict__ cosb, const float* __restrict__ sinb,
    u16* __restrict__ qb, u16* __restrict__ kb, u16* __restrict__ vtb)
{
  GEMM_PROLOGUE(C_, 0, C_)
  const int slice = n0 >> 7;          // 0..23
  const int g = slice / 6, s = slice % 6;
  const int b = m0 >> 11;             // batch (128-row tile never crosses)

#pragma unroll
  for (int mt = 0; mt < 4; ++mt) {
    const int rowbase = m0 + wm * 64 + mt * 16 + quad * 4;
    const int t0 = rowbase & 2047;
    float vv[4][4];
#pragma unroll
    for (int nt = 0; nt < 4; ++nt)
#pragma unroll
      for (int r = 0; r < 4; ++r)
        vv[nt][r] = acc[mt][nt][r] + bias[n0 + wn * 64 + nt * 16 + l16];

    if (s < 5 && wn == 0) {           // RoPE on d<32 (nt 0,1 pair in-lane)
#pragma unroll
      for (int r = 0; r < 4; ++r) {
        const int t = t0 + r;
        float cs0 = cosb[t * 32 + l16],      sn0 = sinb[t * 32 + l16];
        float cs1 = cosb[t * 32 + 16 + l16], sn1 = sinb[t * 32 + 16 + l16];
        float a = vv[0][r], c = vv[1][r];
        vv[0][r] = a * cs0 - c * sn0;
        vv[1][r] = c * cs1 + a * sn1;
      }
    }

    if (s < 4) {                      // q head h = g*4+s -> qb [B,NH,T,D]
      u16* dst = qb + (size_t)(b * NH_ + g * 4 + s) * T_ * HD_;
#pragma unroll
      for (int nt = 0; nt < 4; ++nt)
#pragma unroll
        for (int r = 0; r < 4; ++r)
          dst[(size_t)(t0 + r) * HD_ + wn * 64 + nt * 16 + l16] = f2b(vv[nt][r]);
    } else if (s == 4) {              // k -> kb [B,NG,T,D]
      u16* dst = kb + (size_t)(b * NG_ + g) * T_ * HD_;
#pragma unroll
      for (int nt = 0; nt < 4; ++nt)
#pragma unroll
        for (int r = 0; r < 4; ++r)
          dst[(size_t)(t0 + r) * HD_ + wn * 64 + nt * 16 + l16] = f2b(vv[nt][r]);
    } else {                          // v -> vtb [B,NG,D,T] (transposed)
      u16* dst = vtb + (size_t)(b * NG_ + g) * HD_ * T_;
#pragma unroll
      for (int nt = 0; nt < 4; ++nt) {
        const int d = wn * 64 + nt * 16 + l16;
        ushort4 pk = { f2b(vv[nt][0]), f2b(vv[nt][1]), f2b(vv[nt][2]), f2b(vv[nt][3]) };
        *(ushort4*)(dst + (size_t)d * T_ + t0) = pk;
      }
    }
  }
}

// --- proj GEMM: out = A @ Bt^T + bias + resid (fp32) -----------------------
__global__ __launch_bounds__(256, 2) void gemm_proj(
    const u16* __restrict__ A, const u16* __restrict__ Bt,
    const float* __restrict__ bias, const float* __restrict__ resid,
    float* __restrict__ outF)
{
  GEMM_PROLOGUE(C_, 0, C_)
#pragma unroll
  for (int mt = 0; mt < 4; ++mt)
#pragma unroll
    for (int nt = 0; nt < 4; ++nt)
#pragma unroll
      for (int r = 0; r < 4; ++r) {
        int row = m0 + wm * 64 + mt * 16 + quad * 4 + r;
        int col = n0 + wn * 64 + nt * 16 + l16;
        float v = acc[mt][nt][r] + bias[col] + resid[(size_t)row * C_ + col];
        outF[(size_t)row * C_ + col] = v;
      }
}

// --- FC1 GEMM: out = gelu(A @ Bt^T + bias) -> bf16 -------------------------
__global__ __launch_bounds__(256, 2) void gemm_fc1(
    const u16* __restrict__ A, const u16* __restrict__ Bt,
    const float* __restrict__ bias, u16* __restrict__ outB)
{
  GEMM_PROLOGUE(C_, 0, C_)
#pragma unroll
  for (int mt = 0; mt < 4; ++mt)
#pragma unroll
    for (int nt = 0; nt < 4; ++nt)
#pragma unroll
      for (int r = 0; r < 4; ++r) {
        int row = m0 + wm * 64 + mt * 16 + quad * 4 + r;
        int col = n0 + wn * 64 + nt * 16 + l16;
        float v = acc[mt][nt][r] + bias[col];
        v = 0.5f * v * (1.0f + erff(v * 0.70710678118654752f));
        outB[(size_t)row * FFN_ + col] = f2b(v);
      }
}

// --- FC2 GEMM, split-K=2. slice 0: out = acc + bias + out(resid);
//     slice 1: pbuf = acc.  Reduce kernel adds pbuf into out. --------------
__global__ __launch_bounds__(256, 2) void gemm_fc2(
    const u16* __restrict__ A, const u16* __restrict__ Bt,
    const float* __restrict__ bias, float* __restrict__ outF,
    float* __restrict__ pbuf)
{
  const int kh = FFN_ / 2;
  const int kbeg = blockIdx.z * kh;
  GEMM_PROLOGUE(FFN_, kbeg, kbeg + kh)
#pragma unroll
  for (int mt = 0; mt < 4; ++mt)
#pragma unroll
    for (int nt = 0; nt < 4; ++nt)
#pragma unroll
      for (int r = 0; r < 4; ++r) {
        int row = m0 + wm * 64 + mt * 16 + quad * 4 + r;
        int col = n0 + wn * 64 + nt * 16 + l16;
        size_t idx = (size_t)row * C_ + col;
        if (blockIdx.z == 0)
          outF[idx] = acc[mt][nt][r] + bias[col] + outF[idx];
        else
          pbuf[idx] = acc[mt][nt][r];
      }
}

__global__ __launch_bounds__(256) void add_pbuf(
    float* __restrict__ out, const float* __restrict__ p)
{
  size_t i = ((size_t)blockIdx.x * 256 + threadIdx.x) * 4;
  float4 a = *(float4*)(out + i);
  float4 b = *(const float4*)(p + i);
  a.x += b.x; a.y += b.y; a.z += b.z; a.w += b.w;
  *(float4*)(out + i) = a;
}

// ---------------------------------------------------------------------------
// Flash attention, causal, GQA. BQ=64 (16 rows/wave), BKV=64.
// ---------------------------------------------------------------------------
__global__ __launch_bounds__(256, 2) void attn_kernel(
    const u16* __restrict__ qb, const u16* __restrict__ kb,
    const u16* __restrict__ vt, u16* __restrict__ y)
{
  __shared__ u16 Qs[64 * 128];
  __shared__ u16 Ks[64 * 128];
  __shared__ u16 Vs[128 * 64];      // V^T tile: [d][kv]
  __shared__ u16 Ps[4 * 16 * 64];   // per-wave P

  const int tid = threadIdx.x;
  const int w = tid >> 6, lane = tid & 63, quad = lane >> 4, l16 = lane & 15;
  const int b = blockIdx.y >> 4, h = blockIdx.y & 15, g = h >> 2;
  const int q0 = blockIdx.x * 64;

  const u16* Qg = qb + (size_t)(b * NH_ + h) * T_ * HD_;
  const u16* Kg = kb + (size_t)(b * NG_ + g) * T_ * HD_;
  const u16* Vg = vt + (size_t)(b * NG_ + g) * HD_ * T_;

  {  // stage Q tile once (16 KB)
    const int row = tid >> 4, slot = tid & 15;
#pragma unroll
    for (int i = 0; i < 4; ++i) {
      int r = row + i * 16;
      int chunk = slot ^ (r & 7);
      load_lds16(Qg + (size_t)(q0 + r) * HD_ + chunk * 8, (char*)Qs + i * 4096 + w * 1024);
    }
  }
  __syncthreads();

  // Q fragments are loop-invariant: hoist
  bf16x8 aq[4];
#pragma unroll
  for (int kk = 0; kk < 4; ++kk) {
    int row = w * 16 + l16;
    int slot = (kk * 4 + quad) ^ (row & 7);
    aq[kk] = *(const bf16x8*)(Qs + row * 128 + slot * 8);
  }

  const f32x4 vzero = {0.f, 0.f, 0.f, 0.f};
  float m_run[4] = {-1e30f, -1e30f, -1e30f, -1e30f};
  float l_run[4] = {0.f, 0.f, 0.f, 0.f};
  f32x4 O[8];
#pragma unroll
  for (int nt = 0; nt < 8; ++nt) O[nt] = vzero;

  const float scale = 0.08838834764831845f;  // 1/sqrt(128)
  const int rowK = tid >> 4, slotK = tid & 15;
  const int rowV = tid >> 3, slotV = tid & 7;

  for (int j = 0; j <= (int)blockIdx.x; ++j) {
    const int kv0 = j * 64;
    __syncthreads();
#pragma unroll
    for (int i = 0; i < 4; ++i) {
      int r = rowK + i * 16;
      int chunk = slotK ^ (r & 7);
      load_lds16(Kg + (size_t)(kv0 + r) * HD_ + chunk * 8, (char*)Ks + i * 4096 + w * 1024);
    }
#pragma unroll
    for (int i = 0; i < 4; ++i) {
      int r = rowV + i * 32;
      int chunk = slotV ^ (r & 7);
      load_lds16(Vg + (size_t)r * T_ + kv0 + chunk * 8, (char*)Vs + i * 4096 + w * 1024);
    }
    __syncthreads();

    // S = Q K^T
    f32x4 S[4];
#pragma unroll
    for (int jn = 0; jn < 4; ++jn) {
      f32x4 a = vzero;
#pragma unroll
      for (int kk = 0; kk < 4; ++kk) {
        int row = jn * 16 + l16;
        int slot = (kk * 4 + quad) ^ (row & 7);
        bf16x8 bk = *(const bf16x8*)(Ks + row * 128 + slot * 8);
        a = __builtin_amdgcn_mfma_f32_16x16x32_bf16(aq[kk], bk, a, 0, 0, 0);
      }
      S[jn] = a;
    }

    // scale (+ causal mask only on the diagonal tile)
    if (j == (int)blockIdx.x) {
#pragma unroll
      for (int jn = 0; jn < 4; ++jn) {
        int col = kv0 + jn * 16 + l16;
#pragma unroll
        for (int r = 0; r < 4; ++r) {
          int qrow = q0 + w * 16 + quad * 4 + r;
          float v = S[jn][r] * scale;
          S[jn][r] = (col <= qrow) ? v : -1e30f;
        }
      }
    } else {
#pragma unroll
      for (int jn = 0; jn < 4; ++jn)
#pragma unroll
        for (int r = 0; r < 4; ++r) S[jn][r] *= scale;
    }

    // online softmax (16-lane row reduction per quad)
    float mx[4];
#pragma unroll
    for (int r = 0; r < 4; ++r)
      mx[r] = fmaxf(fmaxf(S[0][r], S[1][r]), fmaxf(S[2][r], S[3][r]));
#pragma unroll
    for (int d = 1; d < 16; d <<= 1)
#pragma unroll
      for (int r = 0; r < 4; ++r) mx[r] = fmaxf(mx[r], __shfl_xor(mx[r], d));

    float alpha[4];
#pragma unroll
    for (int r = 0; r < 4; ++r) {
      float mn = fmaxf(m_run[r], mx[r]);
      alpha[r] = __expf(m_run[r] - mn);
      m_run[r] = mn;
    }
    float rs[4] = {0.f, 0.f, 0.f, 0.f};
#pragma unroll
    for (int jn = 0; jn < 4; ++jn)
#pragma unroll
      for (int r = 0; r < 4; ++r) {
        float p = __expf(S[jn][r] - m_run[r]);
        S[jn][r] = p;
        rs[r] += p;
      }
#pragma unroll
    for (int d = 1; d < 16; d <<= 1)
#pragma unroll
      for (int r = 0; r < 4; ++r) rs[r] += __shfl_xor(rs[r], d);
#pragma unroll
    for (int r = 0; r < 4; ++r) l_run[r] = l_run[r] * alpha[r] + rs[r];
#pragma unroll
    for (int nt = 0; nt < 8; ++nt)
#pragma unroll
      for (int r = 0; r < 4; ++r) O[nt][r] *= alpha[r];

    // P (C-layout) -> LDS -> A-layout; wave-private region
#pragma unroll
    for (int jn = 0; jn < 4; ++jn)
#pragma unroll
      for (int r = 0; r < 4; ++r) {
        int row = quad * 4 + r;
        int col = jn * 16 + l16;
        int slot = (col >> 3) ^ (row & 7);
        Ps[w * 1024 + row * 64 + slot * 8 + (col & 7)] = f2b(S[jn][r]);
      }

    // O += P V
    bf16x8 ap[2];
#pragma unroll
    for (int kk = 0; kk < 2; ++kk) {
      int slot = (kk * 4 + quad) ^ (l16 & 7);
      ap[kk] = *(const bf16x8*)(Ps + w * 1024 + l16 * 64 + slot * 8);
    }
#pragma unroll
    for (int nt = 0; nt < 8; ++nt) {
#pragma unroll
      for (int kk = 0; kk < 2; ++kk) {
        int row = nt * 16 + l16;
        int slot = (kk * 4 + quad) ^ (row & 7);
        bf16x8 bv = *(const bf16x8*)(Vs + row * 64 + slot * 8);
        O[nt] = __builtin_amdgcn_mfma_f32_16x16x32_bf16(ap[kk], bv, O[nt], 0, 0, 0);
      }
    }
  }

  // epilogue: O/l -> y [B,T,C] bf16
#pragma unroll
  for (int r = 0; r < 4; ++r) {
    float inv = 1.0f / l_run[r];
    int t = q0 + w * 16 + quad * 4 + r;
    size_t base = (size_t)(b * T_ + t) * C_ + h * HD_;
#pragma unroll
    for (int nt = 0; nt < 8; ++nt)
      y[base + nt * 16 + l16] = f2b(O[nt][r] * inv);
  }
}

// ---------------------------------------------------------------------------
extern "C" void kernel_launch(void* const* d_in, const int* in_sizes, int n_in,
                              void* d_out, int out_size, void* d_ws, size_t ws_size,
                              hipStream_t stream)
{
  const float* x     = (const float*)d_in[0];
  const float* cosb  = (const float*)d_in[1];
  const float* sinb  = (const float*)d_in[2];
  const float* ln1w  = (const float*)d_in[3];
  const float* ln1b  = (const float*)d_in[4];
  const float* wqkv  = (const float*)d_in[5];
  const float* bqkv  = (const float*)d_in[6];
  const float* wproj = (const float*)d_in[7];
  const float* bproj = (const float*)d_in[8];
  const float* ln2w  = (const float*)d_in[9];
  const float* ln2b  = (const float*)d_in[10];
  const float* wfc1  = (const float*)d_in[11];
  const float* bfc1  = (const float*)d_in[12];
  const float* wfc2  = (const float*)d_in[13];
  const float* bfc2  = (const float*)d_in[14];
  float* out = (float*)d_out;

  char* ws = (char*)d_ws;
  const size_t MiB = 1ull << 20;
  // pbuf (32 MiB fp32) aliases ln1+ln2 (dead before FC2 runs).
  u16*   ln1    = (u16*)  (ws + 0);
  u16*   ln2    = (u16*)  (ws + 16 * MiB);
  float* pbuf   = (float*)(ws + 0);
  size_t off = 32 * MiB;
  auto alloc = [&](size_t bytes) -> char* {
    char* p = ws + off;
    off += (bytes + 255) & ~(size_t)255;
    return p;
  };
  u16* wqkvT  = (u16*)alloc((size_t)QKVO_ * C_ * 2);     // 12 MiB
  u16* wprojT = (u16*)alloc((size_t)C_ * C_ * 2);        //  8 MiB
  u16* wfc1T  = (u16*)alloc((size_t)FFN_ * C_ * 2);      // 32 MiB
  u16* wfc2T  = (u16*)alloc((size_t)C_ * FFN_ * 2);      // 32 MiB
  u16* qbuf   = (u16*)alloc((size_t)B_ * NH_ * T_ * HD_ * 2);  // 16 MiB
  u16* kbuf   = (u16*)alloc((size_t)B_ * NG_ * T_ * HD_ * 2);  //  4 MiB
  u16* vtb    = (u16*)alloc((size_t)B_ * NG_ * HD_ * T_ * 2);  //  4 MiB
  u16* ybuf   = (u16*)alloc((size_t)ROWS_ * C_ * 2);           // 16 MiB
  u16* gbuf   = (u16*)alloc((size_t)ROWS_ * FFN_ * 2);         // 64 MiB
  if (off > ws_size) return;  // workspace too small: fail loudly

  ln2x_kernel<<<dim3(ROWS_), dim3(256), 0, stream>>>(x, ln1w, ln1b, ln2w, ln2b, ln1, ln2);

  tcast64<<<dim3(QKVO_/64, C_/64),  dim3(256), 0, stream>>>(wqkv,  wqkvT,  C_,   QKVO_);
  tcast64<<<dim3(C_/64,   C_/64),   dim3(256), 0, stream>>>(wproj, wprojT, C_,   C_);
  tcast64<<<dim3(FFN_/64, C_/64),   dim3(256), 0, stream>>>(wfc1,  wfc1T,  C_,   FFN_);
  tcast64<<<dim3(C_/64,   FFN_/64), dim3(256), 0, stream>>>(wfc2,  wfc2T,  FFN_, C_);

  gemm_qkv<<<dim3(QKVO_/128, ROWS_/128), dim3(256), 0, stream>>>(
      ln1, wqkvT, bqkv, cosb, sinb, qbuf, kbuf, vtb);

  attn_kernel<<<dim3(T_/64, B_*NH_), dim3(256), 0, stream>>>(qbuf, kbuf, vtb, ybuf);

  // h + x -> d_out (fp32)
  gemm_proj<<<dim3(C_/128, ROWS_/128), dim3(256), 0, stream>>>(
      ybuf, wprojT, bproj, x, out);

  // gelu(ln2 @ w_fc1 + b_fc1) -> gbuf (bf16)
  gemm_fc1<<<dim3(FFN_/128, ROWS_/128), dim3(256), 0, stream>>>(
      ln2, wfc1T, bfc1, gbuf);

  // gbuf @ w_fc2, split-K=2: slice0 adds bias+resid into out, slice1 -> pbuf
  gemm_fc2<<<dim3(C_/128, ROWS_/128, 2), dim3(256), 0, stream>>>(
      gbuf, wfc2T, bfc2, out, pbuf);

  add_pbuf<<<dim3((ROWS_*C_)/1024), dim3(256), 0, stream>>>(out, pbuf);
}

// Round 3
// 851.191 us; speedup vs baseline: 1.1094x; 1.0582x over previous
//
#include <hip/hip_runtime.h>
#include <cstdint>
#include <cstddef>

// ---------------------------------------------------------------------------
// Transformer block, MI355X bf16-MFMA. Round 3:
//  - XCD-region swizzle for FC2/proj/QKV (each XCD owns a contiguous 8m x 8n
//    block region; round-robin lin%8 heuristic) -> cut A-tile refetch (~8x on
//    FC2's gbuf reads, FETCH 474 MB -> ~280 MB predicted).
//  - Attention: BQ=128 (32 q-rows/wave, 2 row-groups sharing K/V fragment
//    reads: 36 ds_read_b128 per 64 MFMA), Ps aliased into dead Qs space
//    (64 KB LDS total), balanced causal pairing: block i does q-tiles
//    {i, 15-i} = uniform 34 kv-tiles/block, grid 8 x 32.
// ---------------------------------------------------------------------------

typedef unsigned short u16;
typedef __bf16 bf16x8 __attribute__((ext_vector_type(8)));
typedef float  f32x4  __attribute__((ext_vector_type(4)));

#define B_      2
#define T_      2048
#define C_      2048
#define NH_     16
#define NG_     4
#define HD_     128
#define QKVO_   3072      // (16 + 2*4) * 128
#define FFN_    8192
#define ROWS_   4096      // B*T

__device__ __forceinline__ u16 f2b(float f) {
  union { float f; uint32_t u; } c; c.f = f;
  uint32_t u = c.u;
  return (u16)((u + 0x7fffu + ((u >> 16) & 1u)) >> 16);  // RNE
}
__device__ __forceinline__ float b2f(u16 h) {
  union { uint32_t u; float f; } c; c.u = ((uint32_t)h) << 16;
  return c.f;
}
__device__ __forceinline__ void load_lds16(const void* g, void* l) {
  __builtin_amdgcn_global_load_lds(
      (const __attribute__((address_space(1))) uint32_t*)g,
      (__attribute__((address_space(3))) uint32_t*)l, 16, 0, 0);
}

// ---------------------------------------------------------------------------
// Kernel 1: dual LayerNorm (one mean/var, two weight sets) -> bf16
// ---------------------------------------------------------------------------
__global__ __launch_bounds__(256) void ln2x_kernel(
    const float* __restrict__ x,
    const float* __restrict__ w1, const float* __restrict__ b1,
    const float* __restrict__ w2, const float* __restrict__ b2,
    u16* __restrict__ o1, u16* __restrict__ o2)
{
  const int row = blockIdx.x;
  const float4* xr = (const float4*)(x + (size_t)row * C_);
  const int t = threadIdx.x;
  float4 v0 = xr[t];
  float4 v1 = xr[t + 256];
  float s  = v0.x + v0.y + v0.z + v0.w + v1.x + v1.y + v1.z + v1.w;
  float ss = v0.x*v0.x + v0.y*v0.y + v0.z*v0.z + v0.w*v0.w
           + v1.x*v1.x + v1.y*v1.y + v1.z*v1.z + v1.w*v1.w;
#pragma unroll
  for (int o = 32; o; o >>= 1) { s += __shfl_down(s, o); ss += __shfl_down(ss, o); }
  __shared__ float red[8];
  const int w = t >> 6;
  if ((t & 63) == 0) { red[w] = s; red[4 + w] = ss; }
  __syncthreads();
  s  = red[0] + red[1] + red[2] + red[3];
  ss = red[4] + red[5] + red[6] + red[7];
  const float mu   = s * (1.0f / C_);
  const float rstd = rsqrtf(ss * (1.0f / C_) - mu * mu + 1e-5f);

  const float4* W1 = (const float4*)w1; const float4* B1 = (const float4*)b1;
  const float4* W2 = (const float4*)w2; const float4* B2 = (const float4*)b2;
#pragma unroll
  for (int c = 0; c < 2; ++c) {
    const int idx = t + c * 256;
    float4 v = (c == 0) ? v0 : v1;
    float n0 = (v.x - mu) * rstd, n1 = (v.y - mu) * rstd;
    float n2 = (v.z - mu) * rstd, n3 = (v.w - mu) * rstd;
    float4 a1 = W1[idx], c1 = B1[idx], a2 = W2[idx], c2 = B2[idx];
    uint64_t p1 = (uint64_t)f2b(n0*a1.x + c1.x)
                | ((uint64_t)f2b(n1*a1.y + c1.y) << 16)
                | ((uint64_t)f2b(n2*a1.z + c1.z) << 32)
                | ((uint64_t)f2b(n3*a1.w + c1.w) << 48);
    uint64_t p2 = (uint64_t)f2b(n0*a2.x + c2.x)
                | ((uint64_t)f2b(n1*a2.y + c2.y) << 16)
                | ((uint64_t)f2b(n2*a2.z + c2.z) << 32)
                | ((uint64_t)f2b(n3*a2.w + c2.w) << 48);
    ((uint64_t*)o1)[(size_t)row * (C_/4) + idx] = p1;
    ((uint64_t*)o2)[(size_t)row * (C_/4) + idx] = p2;
  }
}

// ---------------------------------------------------------------------------
// Kernel 2: transpose + cast fp32->bf16, 64x64 tile
// ---------------------------------------------------------------------------
__global__ __launch_bounds__(256) void tcast64(
    const float* __restrict__ in, u16* __restrict__ out, int R, int Ccols)
{
  __shared__ u16 tileT[64 * 72];
  const int c0 = blockIdx.x * 64, r0 = blockIdx.y * 64;
  const int lin = threadIdx.x;
  {
    const int cI = (lin & 15) * 4, r = lin >> 4;
#pragma unroll
    for (int i = 0; i < 4; ++i) {
      const int rr = r + i * 16;
      float4 v = *(const float4*)(in + (size_t)(r0 + rr) * Ccols + c0 + cI);
      tileT[(cI + 0) * 72 + rr] = f2b(v.x);
      tileT[(cI + 1) * 72 + rr] = f2b(v.y);
      tileT[(cI + 2) * 72 + rr] = f2b(v.z);
      tileT[(cI + 3) * 72 + rr] = f2b(v.w);
    }
  }
  __syncthreads();
  {
    const int rr = (lin & 15) * 4, cc = lin >> 4;
#pragma unroll
    for (int i = 0; i < 4; ++i) {
      const int c = cc + i * 16;
      ushort4 pk = *(const ushort4*)(tileT + c * 72 + rr);
      *(ushort4*)(out + (size_t)(c0 + c) * R + r0 + rr) = pk;
    }
  }
}

// ---------------------------------------------------------------------------
// Shared GEMM main loop (128x128 tile, BK=32)
// ---------------------------------------------------------------------------
__device__ __forceinline__ void gemm_loop(
    const u16* __restrict__ Ap, const u16* __restrict__ Bp,
    int K, int kbeg, int kend, f32x4 acc[4][4])
{
  __shared__ u16 As[128 * 32];
  __shared__ u16 Bs[128 * 32];
  const int tid = threadIdx.x;
  const int w = tid >> 6, lane = tid & 63, quad = lane >> 4, l16 = lane & 15;
  const int wm = w >> 1, wn = w & 1;
  const int rowS = tid >> 2, slotS = tid & 3;

  for (int k0 = kbeg; k0 < kend; k0 += 32) {
    __syncthreads();
#pragma unroll
    for (int i = 0; i < 2; ++i) {
      int row = rowS + i * 64;
      int chunk = slotS ^ ((row >> 1) & 3);
      load_lds16(Ap + (size_t)row * K + k0 + chunk * 8, (char*)As + i * 4096 + w * 1024);
      load_lds16(Bp + (size_t)row * K + k0 + chunk * 8, (char*)Bs + i * 4096 + w * 1024);
    }
    __syncthreads();

    bf16x8 af[4], bf[4];
#pragma unroll
    for (int mt = 0; mt < 4; ++mt) {
      int row = wm * 64 + mt * 16 + l16;
      int slot = quad ^ ((row >> 1) & 3);
      af[mt] = *(const bf16x8*)(As + row * 32 + slot * 8);
    }
#pragma unroll
    for (int nt = 0; nt < 4; ++nt) {
      int row = wn * 64 + nt * 16 + l16;
      int slot = quad ^ ((row >> 1) & 3);
      bf[nt] = *(const bf16x8*)(Bs + row * 32 + slot * 8);
    }
#pragma unroll
    for (int mt = 0; mt < 4; ++mt)
#pragma unroll
      for (int nt = 0; nt < 4; ++nt)
        acc[mt][nt] = __builtin_amdgcn_mfma_f32_16x16x32_bf16(af[mt], bf[nt], acc[mt][nt], 0, 0, 0);
  }
}

#define GEMM_PROLOGUE(KSTRIDE, KBEG, KEND, M0, N0)                            \
  const int tid = threadIdx.x;                                                \
  const int w = tid >> 6, lane = tid & 63, quad = lane >> 4, l16 = lane & 15; \
  const int wm = w >> 1, wn = w & 1;                                          \
  const int m0 = (M0), n0 = (N0);                                             \
  const f32x4 vzero = {0.f, 0.f, 0.f, 0.f};                                   \
  f32x4 acc[4][4];                                                            \
  _Pragma("unroll") for (int i = 0; i < 4; ++i)                               \
    _Pragma("unroll") for (int j = 0; j < 4; ++j) acc[i][j] = vzero;          \
  gemm_loop(A + (size_t)m0 * (KSTRIDE), Bt + (size_t)n0 * (KSTRIDE),          \
            (KSTRIDE), (KBEG), (KEND), acc);

// XCD-region swizzle (lin%8 round-robin heuristic). 8 regions: 4 m x 2 n.
// Region = RM m-blocks x RN n-blocks; grid per z-slice = 8*RM*RN blocks.
#define XCD_SWIZZLE(RM, RN)                                                   \
  const int lin_ = blockIdx.x;                                                \
  const int xcd_ = lin_ & 7, loc_ = lin_ >> 3;                                \
  const int mb_ = (xcd_ >> 1) * (RM) + loc_ / (RN);                           \
  const int nb_ = (xcd_ & 1) * (RN) + loc_ % (RN);

// --- QKV GEMM: epilogue fuses bias + RoPE + head scatter + V transpose -----
__global__ __launch_bounds__(256, 2) void gemm_qkv(
    const u16* __restrict__ A, const u16* __restrict__ Bt,
    const float* __restrict__ bias,
    const float* __restrict__ cosb, const float* __restrict__ sinb,
    u16* __restrict__ qb, u16* __restrict__ kb, u16* __restrict__ vtb)
{
  XCD_SWIZZLE(8, 12)   // Mb=32, Nb=24
  GEMM_PROLOGUE(C_, 0, C_, mb_ * 128, nb_ * 128)
  const int slice = n0 >> 7;          // 0..23
  const int g = slice / 6, s = slice % 6;
  const int b = m0 >> 11;

#pragma unroll
  for (int mt = 0; mt < 4; ++mt) {
    const int rowbase = m0 + wm * 64 + mt * 16 + quad * 4;
    const int t0 = rowbase & 2047;
    float vv[4][4];
#pragma unroll
    for (int nt = 0; nt < 4; ++nt)
#pragma unroll
      for (int r = 0; r < 4; ++r)
        vv[nt][r] = acc[mt][nt][r] + bias[n0 + wn * 64 + nt * 16 + l16];

    if (s < 5 && wn == 0) {           // RoPE on d<32 (nt 0,1 pair in-lane)
#pragma unroll
      for (int r = 0; r < 4; ++r) {
        const int t = t0 + r;
        float cs0 = cosb[t * 32 + l16],      sn0 = sinb[t * 32 + l16];
        float cs1 = cosb[t * 32 + 16 + l16], sn1 = sinb[t * 32 + 16 + l16];
        float a = vv[0][r], c = vv[1][r];
        vv[0][r] = a * cs0 - c * sn0;
        vv[1][r] = c * cs1 + a * sn1;
      }
    }

    if (s < 4) {                      // q head
      u16* dst = qb + (size_t)(b * NH_ + g * 4 + s) * T_ * HD_;
#pragma unroll
      for (int nt = 0; nt < 4; ++nt)
#pragma unroll
        for (int r = 0; r < 4; ++r)
          dst[(size_t)(t0 + r) * HD_ + wn * 64 + nt * 16 + l16] = f2b(vv[nt][r]);
    } else if (s == 4) {              // k
      u16* dst = kb + (size_t)(b * NG_ + g) * T_ * HD_;
#pragma unroll
      for (int nt = 0; nt < 4; ++nt)
#pragma unroll
        for (int r = 0; r < 4; ++r)
          dst[(size_t)(t0 + r) * HD_ + wn * 64 + nt * 16 + l16] = f2b(vv[nt][r]);
    } else {                          // v -> vtb [B,NG,D,T] (transposed)
      u16* dst = vtb + (size_t)(b * NG_ + g) * HD_ * T_;
#pragma unroll
      for (int nt = 0; nt < 4; ++nt) {
        const int d = wn * 64 + nt * 16 + l16;
        ushort4 pk = { f2b(vv[nt][0]), f2b(vv[nt][1]), f2b(vv[nt][2]), f2b(vv[nt][3]) };
        *(ushort4*)(dst + (size_t)d * T_ + t0) = pk;
      }
    }
  }
}

// --- proj GEMM: out = A @ Bt^T + bias + resid (fp32) -----------------------
__global__ __launch_bounds__(256, 2) void gemm_proj(
    const u16* __restrict__ A, const u16* __restrict__ Bt,
    const float* __restrict__ bias, const float* __restrict__ resid,
    float* __restrict__ outF)
{
  XCD_SWIZZLE(8, 8)    // Mb=32, Nb=16
  GEMM_PROLOGUE(C_, 0, C_, mb_ * 128, nb_ * 128)
#pragma unroll
  for (int mt = 0; mt < 4; ++mt)
#pragma unroll
    for (int nt = 0; nt < 4; ++nt)
#pragma unroll
      for (int r = 0; r < 4; ++r) {
        int row = m0 + wm * 64 + mt * 16 + quad * 4 + r;
        int col = n0 + wn * 64 + nt * 16 + l16;
        float v = acc[mt][nt][r] + bias[col] + resid[(size_t)row * C_ + col];
        outF[(size_t)row * C_ + col] = v;
      }
}

// --- FC1 GEMM: out = gelu(A @ Bt^T + bias) -> bf16 (natural order) ---------
__global__ __launch_bounds__(256, 2) void gemm_fc1(
    const u16* __restrict__ A, const u16* __restrict__ Bt,
    const float* __restrict__ bias, u16* __restrict__ outB)
{
  GEMM_PROLOGUE(C_, 0, C_, blockIdx.y * 128, blockIdx.x * 128)
#pragma unroll
  for (int mt = 0; mt < 4; ++mt)
#pragma unroll
    for (int nt = 0; nt < 4; ++nt)
#pragma unroll
      for (int r = 0; r < 4; ++r) {
        int row = m0 + wm * 64 + mt * 16 + quad * 4 + r;
        int col = n0 + wn * 64 + nt * 16 + l16;
        float v = acc[mt][nt][r] + bias[col];
        v = 0.5f * v * (1.0f + erff(v * 0.70710678118654752f));
        outB[(size_t)row * FFN_ + col] = f2b(v);
      }
}

// --- FC2 GEMM, split-K=2, XCD swizzle --------------------------------------
__global__ __launch_bounds__(256, 2) void gemm_fc2(
    const u16* __restrict__ A, const u16* __restrict__ Bt,
    const float* __restrict__ bias, float* __restrict__ outF,
    float* __restrict__ pbuf)
{
  XCD_SWIZZLE(8, 8)    // Mb=32, Nb=16
  const int kh = FFN_ / 2;
  const int kbeg = blockIdx.z * kh;
  GEMM_PROLOGUE(FFN_, kbeg, kbeg + kh, mb_ * 128, nb_ * 128)
#pragma unroll
  for (int mt = 0; mt < 4; ++mt)
#pragma unroll
    for (int nt = 0; nt < 4; ++nt)
#pragma unroll
      for (int r = 0; r < 4; ++r) {
        int row = m0 + wm * 64 + mt * 16 + quad * 4 + r;
        int col = n0 + wn * 64 + nt * 16 + l16;
        size_t idx = (size_t)row * C_ + col;
        if (blockIdx.z == 0)
          outF[idx] = acc[mt][nt][r] + bias[col] + outF[idx];
        else
          pbuf[idx] = acc[mt][nt][r];
      }
}

__global__ __launch_bounds__(256) void add_pbuf(
    float* __restrict__ out, const float* __restrict__ p)
{
  size_t i = ((size_t)blockIdx.x * 256 + threadIdx.x) * 4;
  float4 a = *(float4*)(out + i);
  float4 b = *(const float4*)(p + i);
  a.x += b.x; a.y += b.y; a.z += b.z; a.w += b.w;
  *(float4*)(out + i) = a;
}

// ---------------------------------------------------------------------------
// Flash attention, causal, GQA. BQ=128 (32 q-rows/wave, 2 row-groups), BKV=64.
// Balanced pairing: block bi does q-tiles {bi, 15-bi} (34 kv-tiles uniform).
// LDS: Qs 32K + Ks 16K + Vs 16K = 64K; Ps aliases Qs (dead after frag hoist).
// ---------------------------------------------------------------------------
__global__ __launch_bounds__(256, 2) void attn_kernel(
    const u16* __restrict__ qb, const u16* __restrict__ kb,
    const u16* __restrict__ vt, u16* __restrict__ y)
{
  __shared__ u16 Qs[128 * 128];     // 32 KB; reused as Ps after aq hoist
  __shared__ u16 Ks[64 * 128];      // 16 KB
  __shared__ u16 Vs[128 * 64];      // 16 KB, V^T tile [d][kv]
  u16* Ps = Qs;                     // per-wave 16x64 x 2 row-groups

  const int tid = threadIdx.x;
  const int w = tid >> 6, lane = tid & 63, quad = lane >> 4, l16 = lane & 15;
  const int b = blockIdx.y >> 4, h = blockIdx.y & 15, g = h >> 2;

  const u16* Qg = qb + (size_t)(b * NH_ + h) * T_ * HD_;
  const u16* Kg = kb + (size_t)(b * NG_ + g) * T_ * HD_;
  const u16* Vg = vt + (size_t)(b * NG_ + g) * HD_ * T_;

  const f32x4 vzero = {0.f, 0.f, 0.f, 0.f};
  const float scale = 0.08838834764831845f;  // 1/sqrt(128)
  const int rowQ = tid >> 4, slotQ = tid & 15;   // Q/K staging
  const int rowV = tid >> 3, slotV = tid & 7;    // V staging

#pragma unroll
  for (int p = 0; p < 2; ++p) {
    const int qt = p == 0 ? (int)blockIdx.x : 15 - (int)blockIdx.x;
    const int q0 = qt * 128;

    __syncthreads();   // prior pair's Ps reads complete before Q restage
    // stage Q tile (128x128, 8 issues)
#pragma unroll
    for (int i = 0; i < 8; ++i) {
      int r = rowQ + i * 16;
      int chunk = slotQ ^ (r & 7);
      load_lds16(Qg + (size_t)(q0 + r) * HD_ + chunk * 8, (char*)Qs + i * 4096 + w * 1024);
    }
    __syncthreads();

    // hoist Q fragments: 2 row-groups x 4 k-chunks
    bf16x8 aq[2][4];
#pragma unroll
    for (int rg = 0; rg < 2; ++rg)
#pragma unroll
      for (int kk = 0; kk < 4; ++kk) {
        int row = w * 32 + rg * 16 + l16;
        int slot = (kk * 4 + quad) ^ (row & 7);
        aq[rg][kk] = *(const bf16x8*)(Qs + row * 128 + slot * 8);
      }

    float m_run[2][4], l_run[2][4];
    f32x4 O[2][8];
#pragma unroll
    for (int rg = 0; rg < 2; ++rg)
#pragma unroll
      for (int r = 0; r < 4; ++r) { m_run[rg][r] = -1e30f; l_run[rg][r] = 0.f; }
#pragma unroll
    for (int rg = 0; rg < 2; ++rg)
#pragma unroll
      for (int nt = 0; nt < 8; ++nt) O[rg][nt] = vzero;

    const int jmax = 2 * qt + 1;
    for (int j = 0; j <= jmax; ++j) {
      const int kv0 = j * 64;
      __syncthreads();
#pragma unroll
      for (int i = 0; i < 4; ++i) {
        int r = rowQ + i * 16;
        int chunk = slotQ ^ (r & 7);
        load_lds16(Kg + (size_t)(kv0 + r) * HD_ + chunk * 8, (char*)Ks + i * 4096 + w * 1024);
      }
#pragma unroll
      for (int i = 0; i < 4; ++i) {
        int r = rowV + i * 32;
        int chunk = slotV ^ (r & 7);
        load_lds16(Vg + (size_t)r * T_ + kv0 + chunk * 8, (char*)Vs + i * 4096 + w * 1024);
      }
      __syncthreads();

      // S = Q K^T; bk shared across the 2 row-groups
      f32x4 S[2][4];
#pragma unroll
      for (int jn = 0; jn < 4; ++jn) {
        f32x4 s0 = vzero, s1 = vzero;
#pragma unroll
        for (int kk = 0; kk < 4; ++kk) {
          int row = jn * 16 + l16;
          int slot = (kk * 4 + quad) ^ (row & 7);
          bf16x8 bk = *(const bf16x8*)(Ks + row * 128 + slot * 8);
          s0 = __builtin_amdgcn_mfma_f32_16x16x32_bf16(aq[0][kk], bk, s0, 0, 0, 0);
          s1 = __builtin_amdgcn_mfma_f32_16x16x32_bf16(aq[1][kk], bk, s1, 0, 0, 0);
        }
        S[0][jn] = s0; S[1][jn] = s1;
      }

      // scale (+ mask on the two diagonal-adjacent tiles)
      if (j >= 2 * qt) {
#pragma unroll
        for (int rg = 0; rg < 2; ++rg)
#pragma unroll
          for (int jn = 0; jn < 4; ++jn) {
            int col = kv0 + jn * 16 + l16;
#pragma unroll
            for (int r = 0; r < 4; ++r) {
              int qrow = q0 + w * 32 + rg * 16 + quad * 4 + r;
              float v = S[rg][jn][r] * scale;
              S[rg][jn][r] = (col <= qrow) ? v : -1e30f;
            }
          }
      } else {
#pragma unroll
        for (int rg = 0; rg < 2; ++rg)
#pragma unroll
          for (int jn = 0; jn < 4; ++jn)
#pragma unroll
            for (int r = 0; r < 4; ++r) S[rg][jn][r] *= scale;
      }

      // online softmax per row-group
#pragma unroll
      for (int rg = 0; rg < 2; ++rg) {
        float mx[4];
#pragma unroll
        for (int r = 0; r < 4; ++r)
          mx[r] = fmaxf(fmaxf(S[rg][0][r], S[rg][1][r]), fmaxf(S[rg][2][r], S[rg][3][r]));
#pragma unroll
        for (int d = 1; d < 16; d <<= 1)
#pragma unroll
          for (int r = 0; r < 4; ++r) mx[r] = fmaxf(mx[r], __shfl_xor(mx[r], d));

        float alpha[4];
#pragma unroll
        for (int r = 0; r < 4; ++r) {
          float mn = fmaxf(m_run[rg][r], mx[r]);
          alpha[r] = __expf(m_run[rg][r] - mn);
          m_run[rg][r] = mn;
        }
        float rs[4] = {0.f, 0.f, 0.f, 0.f};
#pragma unroll
        for (int jn = 0; jn < 4; ++jn)
#pragma unroll
          for (int r = 0; r < 4; ++r) {
            float pv = __expf(S[rg][jn][r] - m_run[rg][r]);
            S[rg][jn][r] = pv;
            rs[r] += pv;
          }
#pragma unroll
        for (int d = 1; d < 16; d <<= 1)
#pragma unroll
          for (int r = 0; r < 4; ++r) rs[r] += __shfl_xor(rs[r], d);
#pragma unroll
        for (int r = 0; r < 4; ++r) l_run[rg][r] = l_run[rg][r] * alpha[r] + rs[r];
#pragma unroll
        for (int nt = 0; nt < 8; ++nt)
#pragma unroll
          for (int r = 0; r < 4; ++r) O[rg][nt][r] *= alpha[r];

        // P (C-layout) -> LDS (A-layout), wave-private region in Qs space
#pragma unroll
        for (int jn = 0; jn < 4; ++jn)
#pragma unroll
          for (int r = 0; r < 4; ++r) {
            int row = quad * 4 + r;
            int col = jn * 16 + l16;
            int slot = (col >> 3) ^ (row & 7);
            Ps[w * 2048 + rg * 1024 + row * 64 + slot * 8 + (col & 7)] = f2b(S[rg][jn][r]);
          }
      }

      // O += P V; bv shared across the 2 row-groups
      bf16x8 ap[2][2];
#pragma unroll
      for (int rg = 0; rg < 2; ++rg)
#pragma unroll
        for (int kk = 0; kk < 2; ++kk) {
          int slot = (kk * 4 + quad) ^ (l16 & 7);
          ap[rg][kk] = *(const bf16x8*)(Ps + w * 2048 + rg * 1024 + l16 * 64 + slot * 8);
        }
#pragma unroll
      for (int nt = 0; nt < 8; ++nt) {
#pragma unroll
        for (int kk = 0; kk < 2; ++kk) {
          int row = nt * 16 + l16;
          int slot = (kk * 4 + quad) ^ (row & 7);
          bf16x8 bv = *(const bf16x8*)(Vs + row * 64 + slot * 8);
          O[0][nt] = __builtin_amdgcn_mfma_f32_16x16x32_bf16(ap[0][kk], bv, O[0][nt], 0, 0, 0);
          O[1][nt] = __builtin_amdgcn_mfma_f32_16x16x32_bf16(ap[1][kk], bv, O[1][nt], 0, 0, 0);
        }
      }
    }

    // epilogue
#pragma unroll
    for (int rg = 0; rg < 2; ++rg)
#pragma unroll
      for (int r = 0; r < 4; ++r) {
        float inv = 1.0f / l_run[rg][r];
        int t = q0 + w * 32 + rg * 16 + quad * 4 + r;
        size_t base = (size_t)(b * T_ + t) * C_ + h * HD_;
#pragma unroll
        for (int nt = 0; nt < 8; ++nt)
          y[base + nt * 16 + l16] = f2b(O[rg][nt][r] * inv);
      }
  }
}

// ---------------------------------------------------------------------------
extern "C" void kernel_launch(void* const* d_in, const int* in_sizes, int n_in,
                              void* d_out, int out_size, void* d_ws, size_t ws_size,
                              hipStream_t stream)
{
  const float* x     = (const float*)d_in[0];
  const float* cosb  = (const float*)d_in[1];
  const float* sinb  = (const float*)d_in[2];
  const float* ln1w  = (const float*)d_in[3];
  const float* ln1b  = (const float*)d_in[4];
  const float* wqkv  = (const float*)d_in[5];
  const float* bqkv  = (const float*)d_in[6];
  const float* wproj = (const float*)d_in[7];
  const float* bproj = (const float*)d_in[8];
  const float* ln2w  = (const float*)d_in[9];
  const float* ln2b  = (const float*)d_in[10];
  const float* wfc1  = (const float*)d_in[11];
  const float* bfc1  = (const float*)d_in[12];
  const float* wfc2  = (const float*)d_in[13];
  const float* bfc2  = (const float*)d_in[14];
  float* out = (float*)d_out;

  char* ws = (char*)d_ws;
  const size_t MiB = 1ull << 20;
  u16*   ln1    = (u16*)  (ws + 0);
  u16*   ln2    = (u16*)  (ws + 16 * MiB);
  float* pbuf   = (float*)(ws + 0);      // aliases ln1+ln2 (dead by FC2)
  size_t off = 32 * MiB;
  auto alloc = [&](size_t bytes) -> char* {
    char* p = ws + off;
    off += (bytes + 255) & ~(size_t)255;
    return p;
  };
  u16* wqkvT  = (u16*)alloc((size_t)QKVO_ * C_ * 2);
  u16* wprojT = (u16*)alloc((size_t)C_ * C_ * 2);
  u16* wfc1T  = (u16*)alloc((size_t)FFN_ * C_ * 2);
  u16* wfc2T  = (u16*)alloc((size_t)C_ * FFN_ * 2);
  u16* qbuf   = (u16*)alloc((size_t)B_ * NH_ * T_ * HD_ * 2);
  u16* kbuf   = (u16*)alloc((size_t)B_ * NG_ * T_ * HD_ * 2);
  u16* vtb    = (u16*)alloc((size_t)B_ * NG_ * HD_ * T_ * 2);
  u16* ybuf   = (u16*)alloc((size_t)ROWS_ * C_ * 2);
  u16* gbuf   = (u16*)alloc((size_t)ROWS_ * FFN_ * 2);
  if (off > ws_size) return;

  ln2x_kernel<<<dim3(ROWS_), dim3(256), 0, stream>>>(x, ln1w, ln1b, ln2w, ln2b, ln1, ln2);

  tcast64<<<dim3(QKVO_/64, C_/64),  dim3(256), 0, stream>>>(wqkv,  wqkvT,  C_,   QKVO_);
  tcast64<<<dim3(C_/64,   C_/64),   dim3(256), 0, stream>>>(wproj, wprojT, C_,   C_);
  tcast64<<<dim3(FFN_/64, C_/64),   dim3(256), 0, stream>>>(wfc1,  wfc1T,  C_,   FFN_);
  tcast64<<<dim3(C_/64,   FFN_/64), dim3(256), 0, stream>>>(wfc2,  wfc2T,  FFN_, C_);

  gemm_qkv<<<dim3(768), dim3(256), 0, stream>>>(
      ln1, wqkvT, bqkv, cosb, sinb, qbuf, kbuf, vtb);

  attn_kernel<<<dim3(8, B_*NH_), dim3(256), 0, stream>>>(qbuf, kbuf, vtb, ybuf);

  gemm_proj<<<dim3(512), dim3(256), 0, stream>>>(
      ybuf, wprojT, bproj, x, out);

  gemm_fc1<<<dim3(FFN_/128, ROWS_/128), dim3(256), 0, stream>>>(
      ln2, wfc1T, bfc1, gbuf);

  gemm_fc2<<<dim3(512, 1, 2), dim3(256), 0, stream>>>(
      gbuf, wfc2T, bfc2, out, pbuf);

  add_pbuf<<<dim3((ROWS_*C_)/1024), dim3(256), 0, stream>>>(out, pbuf);
}